// Round 1
// baseline (205.801 us; speedup 1.0000x reference)
//
#include <hip/hip_runtime.h>

// Problem constants: B=2, T=2048, D=1024, H=16, DH=64
#define TT 2048
#define DD 1024
#define HH 16
#define DHH 64

typedef __attribute__((ext_vector_type(4))) float  f32x4;
typedef __attribute__((ext_vector_type(8))) short  bf16x8;   // 8 bf16 in 4 VGPRs
typedef __attribute__((ext_vector_type(4))) float  f4;
typedef __attribute__((ext_vector_type(4))) unsigned short u16x4;

// fp32 -> bf16 round-to-nearest-even
__device__ __forceinline__ unsigned short f2b(float f) {
    union { float f; unsigned int u; } v; v.f = f;
    unsigned int r = v.u + 0x7fffu + ((v.u >> 16) & 1u);
    return (unsigned short)(r >> 16);
}

// async global->LDS, 16B per lane; LDS dest must be wave-uniform base + lane*16
__device__ __forceinline__ void gl_lds16(const void* g, void* l) {
    __builtin_amdgcn_global_load_lds(
        (const __attribute__((address_space(1))) unsigned int*)g,
        (__attribute__((address_space(3))) unsigned int*)l, 16, 0, 0);
}

// ---------------- fp32 -> bf16 conversion (vectorized) ----------------
__global__ void f2b_kernel(const float* __restrict__ s, unsigned short* __restrict__ d, int n4) {
    int i = blockIdx.x * blockDim.x + threadIdx.x;
    int stride = gridDim.x * blockDim.x;
    for (; i < n4; i += stride) {
        f4 v = ((const f4*)s)[i];
        u16x4 o;
        o[0] = f2b(v[0]); o[1] = f2b(v[1]); o[2] = f2b(v[2]); o[3] = f2b(v[3]);
        ((u16x4*)d)[i] = o;
    }
}

// ---------------- GEMM: C[M,N] = A[M,K] * Bm[N,K]^T + bias ----------------
// m97 structure: 128x128 tile, 4 waves in 2x2, each wave 64x64 (4x4 frags of 16x16x32)
// mode 0: QKV epilogue -> scatter q (scaled 1/8), k [B,H,T,DH], v transposed [B,H,DH,T], bf16
// mode 1: fp32 out + bias (final projection)
__global__ __launch_bounds__(256) void gemm_bt(
    const unsigned short* __restrict__ A, const unsigned short* __restrict__ Bm,
    const float* __restrict__ bias, int N, int K, int mode,
    unsigned short* __restrict__ q, unsigned short* __restrict__ k,
    unsigned short* __restrict__ vt, float* __restrict__ outf)
{
    __shared__ unsigned short As[128 * 32];
    __shared__ unsigned short Bs[128 * 32];

    int tid = threadIdx.x;
    int l = tid & 63, w = tid >> 6;
    int wr = w >> 1, wc = w & 1;
    int lr = l & 15, lk = (l >> 4) * 8;
    int bm = blockIdx.y, bn = blockIdx.x;

    f32x4 acc[4][4] = {};

    const unsigned short* Ag = A + (size_t)(bm * 128) * K;
    const unsigned short* Bg = Bm + (size_t)(bn * 128) * K;

    for (int k0 = 0; k0 < K; k0 += 32) {
        // stage 128x32 bf16 tiles (8KB each): 2 rounds of 256 lanes x 16B
#pragma unroll
        for (int r = 0; r < 2; ++r) {
            int e = r * 256 + tid;            // element group: 8 bf16 = 16B
            int row = e >> 2, kc = (e & 3) * 8;
            gl_lds16(Ag + (size_t)row * K + k0 + kc, &As[e * 8]);
            gl_lds16(Bg + (size_t)row * K + k0 + kc, &Bs[e * 8]);
        }
        __syncthreads();

        bf16x8 a[4], b[4];
#pragma unroll
        for (int i = 0; i < 4; ++i)
            a[i] = *(const bf16x8*)&As[(wr * 64 + i * 16 + lr) * 32 + lk];
#pragma unroll
        for (int j = 0; j < 4; ++j)
            b[j] = *(const bf16x8*)&Bs[(wc * 64 + j * 16 + lr) * 32 + lk];
#pragma unroll
        for (int i = 0; i < 4; ++i)
#pragma unroll
            for (int j = 0; j < 4; ++j)
                acc[i][j] = __builtin_amdgcn_mfma_f32_16x16x32_bf16(a[i], b[j], acc[i][j], 0, 0, 0);
        __syncthreads();
    }

    // epilogue: D layout col = lane&15, row = (lane>>4)*4 + reg
#pragma unroll
    for (int i = 0; i < 4; ++i) {
#pragma unroll
        for (int j = 0; j < 4; ++j) {
            int row0 = bm * 128 + wr * 64 + i * 16 + (l >> 4) * 4;
            int col  = bn * 128 + wc * 64 + j * 16 + (l & 15);
            float bv = bias[col];
#pragma unroll
            for (int r = 0; r < 4; ++r) {
                float val = acc[i][j][r] + bv;
                int m = row0 + r;
                if (mode == 0) {
                    int which = col >> 10, rem = col & 1023;
                    int h = rem >> 6, d = rem & 63;
                    int b = m >> 11, t = m & 2047;
                    if (which == 0) {
                        // pre-scale q by 1/sqrt(DH) = 0.125 (exact in bf16 scaling)
                        q[((size_t)((b * HH + h) * TT + t)) * DHH + d] = f2b(val * 0.125f);
                    } else if (which == 1) {
                        k[((size_t)((b * HH + h) * TT + t)) * DHH + d] = f2b(val);
                    } else {
                        vt[((size_t)((b * HH + h) * DHH + d)) * TT + t] = f2b(val);
                    }
                } else {
                    outf[(size_t)m * N + col] = val;
                }
            }
        }
    }
}

// ---------------- flash attention ----------------
// grid: (T/128, B*H). block: 256 threads = 4 waves, each wave owns 32 Q rows.
// K tile [64 trow][64 d], Vt tile [64 d][64 key], both XOR-swizzled in LDS
// (linear global_load_lds dest + pre-swizzled global source; read applies same XOR).
__global__ __launch_bounds__(256) void attn(
    const unsigned short* __restrict__ qb,
    const unsigned short* __restrict__ kb,
    const unsigned short* __restrict__ vtb,
    unsigned short* __restrict__ ob)
{
    __shared__ unsigned short Ks[64 * 64];
    __shared__ unsigned short Vs[64 * 64];
    __shared__ unsigned short Ps[4 * 32 * 64];   // per-wave P buffer (swizzled)

    int tid = threadIdx.x;
    int l = tid & 63, w = tid >> 6;
    int bh = blockIdx.y;
    int q0 = blockIdx.x * 128;

    // Q A-fragments in registers: row = lane&15, k(d) = (lane>>4)*8 contiguous
    bf16x8 aq[2][2];
    const unsigned short* qg = qb + ((size_t)bh * TT + q0 + w * 32) * DHH;
#pragma unroll
    for (int mi = 0; mi < 2; ++mi)
#pragma unroll
        for (int kj = 0; kj < 2; ++kj)
            aq[mi][kj] = *(const bf16x8*)(qg + (mi * 16 + (l & 15)) * DHH + kj * 32 + (l >> 4) * 8);

    f32x4 oacc[2][4] = {};
    float mrow[2][4], lrow[2][4];
#pragma unroll
    for (int mi = 0; mi < 2; ++mi)
#pragma unroll
        for (int r = 0; r < 4; ++r) { mrow[mi][r] = -1e30f; lrow[mi][r] = 0.f; }

    const char* kgl = (const char*)(kb + (size_t)bh * TT * DHH);
    const char* vgl = (const char*)(vtb + (size_t)bh * DHH * TT);
    unsigned short* pw = Ps + w * 2048;

    for (int kt0 = 0; kt0 < TT; kt0 += 64) {
        // stage K tile and Vt tile: rows are 128B; source pre-swizzled so that
        // read at byte (row*128 + c*2)^((row&7)<<4) returns logical element (row,c)
#pragma unroll
        for (int r = 0; r < 2; ++r) {
            int p = r * 4096 + tid * 16;       // linear LDS byte position
            int rw = p >> 7, qq = p & 127;
            int sw = qq ^ ((rw & 7) << 4);     // pre-swizzled source column bytes
            gl_lds16(kgl + (size_t)(kt0 + rw) * 128 + sw, (char*)Ks + p);
            gl_lds16(vgl + (size_t)rw * (TT * 2) + kt0 * 2 + sw, (char*)Vs + p);
        }
        __syncthreads();

        // S = Q K^T  (scale already folded into q)
        f32x4 s[2][4] = {};
#pragma unroll
        for (int kj = 0; kj < 2; ++kj) {
#pragma unroll
            for (int nj = 0; nj < 4; ++nj) {
                int trow = nj * 16 + (l & 15);
                int c2 = (kj * 32 + (l >> 4) * 8) * 2;
                bf16x8 bk = *(const bf16x8*)((const char*)Ks + trow * 128 + (c2 ^ ((trow & 7) << 4)));
#pragma unroll
                for (int mi = 0; mi < 2; ++mi)
                    s[mi][nj] = __builtin_amdgcn_mfma_f32_16x16x32_bf16(aq[mi][kj], bk, s[mi][nj], 0, 0, 0);
            }
        }

        // online softmax: each lane holds cols (l&15)+16*nj of rows (l>>4)*4+r (+mi*16)
        float tm[2][4], ps[2][4];
#pragma unroll
        for (int mi = 0; mi < 2; ++mi)
#pragma unroll
            for (int r = 0; r < 4; ++r)
                tm[mi][r] = fmaxf(fmaxf(s[mi][0][r], s[mi][1][r]), fmaxf(s[mi][2][r], s[mi][3][r]));
#pragma unroll
        for (int mask = 1; mask < 16; mask <<= 1)
#pragma unroll
            for (int mi = 0; mi < 2; ++mi)
#pragma unroll
                for (int r = 0; r < 4; ++r)
                    tm[mi][r] = fmaxf(tm[mi][r], __shfl_xor(tm[mi][r], mask, 64));

#pragma unroll
        for (int mi = 0; mi < 2; ++mi)
#pragma unroll
            for (int r = 0; r < 4; ++r) {
                float nm = fmaxf(mrow[mi][r], tm[mi][r]);
                float corr = __expf(mrow[mi][r] - nm);
                mrow[mi][r] = nm;
                lrow[mi][r] *= corr;
#pragma unroll
                for (int dj = 0; dj < 4; ++dj)
                    oacc[mi][dj][r] *= corr;
                ps[mi][r] = 0.f;
            }

        // P = exp(s - m): accumulate row-sum and spill to per-wave swizzled LDS (bf16)
#pragma unroll
        for (int mi = 0; mi < 2; ++mi)
#pragma unroll
            for (int nj = 0; nj < 4; ++nj)
#pragma unroll
                for (int r = 0; r < 4; ++r) {
                    float p = __expf(s[mi][nj][r] - mrow[mi][r]);
                    ps[mi][r] += p;
                    int rw = mi * 16 + (l >> 4) * 4 + r;
                    int col = nj * 16 + (l & 15);
                    *(unsigned short*)((char*)pw + rw * 128 + ((col * 2) ^ ((rw & 7) << 4))) = f2b(p);
                }
#pragma unroll
        for (int mask = 1; mask < 16; mask <<= 1)
#pragma unroll
            for (int mi = 0; mi < 2; ++mi)
#pragma unroll
                for (int r = 0; r < 4; ++r)
                    ps[mi][r] += __shfl_xor(ps[mi][r], mask, 64);
#pragma unroll
        for (int mi = 0; mi < 2; ++mi)
#pragma unroll
            for (int r = 0; r < 4; ++r)
                lrow[mi][r] += ps[mi][r];

        // O += P @ V : A = P (from per-wave LDS), B = Vt (d as col, key as k)
#pragma unroll
        for (int kj = 0; kj < 2; ++kj) {
            bf16x8 ap[2];
#pragma unroll
            for (int mi = 0; mi < 2; ++mi) {
                int rw = mi * 16 + (l & 15);
                int c2 = (kj * 32 + (l >> 4) * 8) * 2;
                ap[mi] = *(const bf16x8*)((const char*)pw + rw * 128 + (c2 ^ ((rw & 7) << 4)));
            }
#pragma unroll
            for (int dj = 0; dj < 4; ++dj) {
                int d = dj * 16 + (l & 15);
                int c2 = (kj * 32 + (l >> 4) * 8) * 2;
                bf16x8 bv = *(const bf16x8*)((const char*)Vs + d * 128 + (c2 ^ ((d & 7) << 4)));
#pragma unroll
                for (int mi = 0; mi < 2; ++mi)
                    oacc[mi][dj] = __builtin_amdgcn_mfma_f32_16x16x32_bf16(ap[mi], bv, oacc[mi][dj], 0, 0, 0);
            }
        }
        __syncthreads();
    }

    // normalize and write O in [B,T,H*DH] layout (A-operand for final projection)
    int b = bh >> 4, h = bh & 15;
#pragma unroll
    for (int mi = 0; mi < 2; ++mi)
#pragma unroll
        for (int dj = 0; dj < 4; ++dj)
#pragma unroll
            for (int r = 0; r < 4; ++r) {
                int t = q0 + w * 32 + mi * 16 + (l >> 4) * 4 + r;
                int col = h * DHH + dj * 16 + (l & 15);
                float o = oacc[mi][dj][r] / lrow[mi][r];
                ob[((size_t)(b * TT + t)) * DD + col] = f2b(o);
            }
}

// ---------------- launcher ----------------
extern "C" void kernel_launch(void* const* d_in, const int* in_sizes, int n_in,
                              void* d_out, int out_size, void* d_ws, size_t ws_size,
                              hipStream_t stream) {
    const float* x    = (const float*)d_in[0];
    const float* Wqkv = (const float*)d_in[1];
    const float* bqkv = (const float*)d_in[2];
    const float* Wo   = (const float*)d_in[3];
    const float* bo   = (const float*)d_in[4];
    float* out = (float*)d_out;

    // workspace layout (bf16 elements), total ~48 MB
    unsigned short* xb  = (unsigned short*)d_ws;        // [4096,1024]
    unsigned short* wqb = xb  + 4096 * 1024;            // [3072,1024]
    unsigned short* wob = wqb + 3072 * 1024;            // [1024,1024]
    unsigned short* q   = wob + 1024 * 1024;            // [B,H,T,DH]
    unsigned short* k   = q   + 2 * 16 * 2048 * 64;     // [B,H,T,DH]
    unsigned short* vt  = k   + 2 * 16 * 2048 * 64;     // [B,H,DH,T]
    unsigned short* ob  = vt  + 2 * 16 * 2048 * 64;     // [4096,1024]

    f2b_kernel<<<dim3(1024), dim3(256), 0, stream>>>(x,    xb,  4096 * 1024 / 4);
    f2b_kernel<<<dim3(768),  dim3(256), 0, stream>>>(Wqkv, wqb, 3072 * 1024 / 4);
    f2b_kernel<<<dim3(256),  dim3(256), 0, stream>>>(Wo,   wob, 1024 * 1024 / 4);

    // QKV projection: M=4096, N=3072, K=1024
    gemm_bt<<<dim3(24, 32), dim3(256), 0, stream>>>(xb, wqb, bqkv, 3072, 1024, 0,
                                                    q, k, vt, nullptr);
    // attention: 512 blocks
    attn<<<dim3(16, 32), dim3(256), 0, stream>>>(q, k, vt, ob);

    // output projection: M=4096, N=1024, K=1024
    gemm_bt<<<dim3(8, 32), dim3(256), 0, stream>>>(ob, wob, bo, 1024, 1024, 1,
                                                   nullptr, nullptr, nullptr, out);
}

// Round 2
// 140.403 us; speedup vs baseline: 1.4658x; 1.4658x over previous
//
#include <hip/hip_runtime.h>

// Problem constants: B=2, T=2048, D=1024, H=16, DH=64
#define TT 2048
#define DD 1024
#define HH 16
#define DHH 64

typedef __attribute__((ext_vector_type(4)))  float  f32x4;
typedef __attribute__((ext_vector_type(16))) float  f32x16;
typedef __attribute__((ext_vector_type(8)))  short  bf16x8;   // 8 bf16 in 4 VGPRs
typedef __attribute__((ext_vector_type(4)))  float  f4;
typedef __attribute__((ext_vector_type(4)))  unsigned short u16x4;
typedef __attribute__((ext_vector_type(4)))  unsigned int   u32x4;

// fp32 -> bf16 round-to-nearest-even
__device__ __forceinline__ unsigned short f2b(float f) {
    union { float f; unsigned int u; } v; v.f = f;
    unsigned int r = v.u + 0x7fffu + ((v.u >> 16) & 1u);
    return (unsigned short)(r >> 16);
}

// async global->LDS, 16B per lane; LDS dest must be wave-uniform base + lane*16
__device__ __forceinline__ void gl_lds16(const void* g, void* l) {
    __builtin_amdgcn_global_load_lds(
        (const __attribute__((address_space(1))) unsigned int*)g,
        (__attribute__((address_space(3))) unsigned int*)l, 16, 0, 0);
}

__device__ __forceinline__ f32x16 mfma32(bf16x8 a, bf16x8 b, f32x16 c) {
    return __builtin_amdgcn_mfma_f32_32x32x16_bf16(a, b, c, 0, 0, 0);
}

// 2^x via v_exp_f32
__device__ __forceinline__ float fexp2(float x) {
    float r; asm("v_exp_f32 %0, %1" : "=v"(r) : "v"(x)); return r;
}

// pack two f32 -> u32 of 2 bf16 (lo = a, hi = b)
__device__ __forceinline__ unsigned int pkbf(float a, float b) {
    unsigned int r;
    asm("v_cvt_pk_bf16_f32 %0, %1, %2" : "=v"(r) : "v"(a), "v"(b));
    return r;
}

// v_permlane32_swap_b32: a'[32+i]=b[i]; b'[i]=a[32+i]
__device__ __forceinline__ void pl32swap(unsigned int& a, unsigned int& b) {
    asm("v_permlane32_swap_b32 %0, %1" : "+v"(a), "+v"(b));
}

__device__ __forceinline__ bf16x8 u2h(u32x4 u) {
    union { u32x4 u; bf16x8 h; } x; x.u = u; return x.h;
}

// ---------------- fp32 -> bf16 conversion (vectorized) ----------------
__global__ void f2b_kernel(const float* __restrict__ s, unsigned short* __restrict__ d, int n4) {
    int i = blockIdx.x * blockDim.x + threadIdx.x;
    int stride = gridDim.x * blockDim.x;
    for (; i < n4; i += stride) {
        f4 v = ((const f4*)s)[i];
        u16x4 o;
        o[0] = f2b(v[0]); o[1] = f2b(v[1]); o[2] = f2b(v[2]); o[3] = f2b(v[3]);
        ((u16x4*)d)[i] = o;
    }
}

// ---------------- GEMM: C[M,N] = A[M,K] * Bm[N,K]^T + bias ----------------
// mode 0: QKV epilogue -> scatter q (scaled by 0.125*log2e), k [B,H,T,DH], v transposed [B,H,DH,T]
// mode 1: fp32 out + bias (final projection)
__global__ __launch_bounds__(256) void gemm_bt(
    const unsigned short* __restrict__ A, const unsigned short* __restrict__ Bm,
    const float* __restrict__ bias, int N, int K, int mode,
    unsigned short* __restrict__ q, unsigned short* __restrict__ k,
    unsigned short* __restrict__ vt, float* __restrict__ outf)
{
    __shared__ unsigned short As[128 * 32];
    __shared__ unsigned short Bs[128 * 32];

    int tid = threadIdx.x;
    int l = tid & 63, w = tid >> 6;
    int wr = w >> 1, wc = w & 1;
    int lr = l & 15, lk = (l >> 4) * 8;
    int bm = blockIdx.y, bn = blockIdx.x;

    f32x4 acc[4][4] = {};

    const unsigned short* Ag = A + (size_t)(bm * 128) * K;
    const unsigned short* Bg = Bm + (size_t)(bn * 128) * K;

    for (int k0 = 0; k0 < K; k0 += 32) {
#pragma unroll
        for (int r = 0; r < 2; ++r) {
            int e = r * 256 + tid;            // element group: 8 bf16 = 16B
            int row = e >> 2, kc = (e & 3) * 8;
            gl_lds16(Ag + (size_t)row * K + k0 + kc, &As[e * 8]);
            gl_lds16(Bg + (size_t)row * K + k0 + kc, &Bs[e * 8]);
        }
        __syncthreads();

        bf16x8 a[4], b[4];
#pragma unroll
        for (int i = 0; i < 4; ++i)
            a[i] = *(const bf16x8*)&As[(wr * 64 + i * 16 + lr) * 32 + lk];
#pragma unroll
        for (int j = 0; j < 4; ++j)
            b[j] = *(const bf16x8*)&Bs[(wc * 64 + j * 16 + lr) * 32 + lk];
#pragma unroll
        for (int i = 0; i < 4; ++i)
#pragma unroll
            for (int j = 0; j < 4; ++j)
                acc[i][j] = __builtin_amdgcn_mfma_f32_16x16x32_bf16(a[i], b[j], acc[i][j], 0, 0, 0);
        __syncthreads();
    }

#pragma unroll
    for (int i = 0; i < 4; ++i) {
#pragma unroll
        for (int j = 0; j < 4; ++j) {
            int row0 = bm * 128 + wr * 64 + i * 16 + (l >> 4) * 4;
            int col  = bn * 128 + wc * 64 + j * 16 + (l & 15);
            float bv = bias[col];
#pragma unroll
            for (int r = 0; r < 4; ++r) {
                float val = acc[i][j][r] + bv;
                int m = row0 + r;
                if (mode == 0) {
                    int which = col >> 10, rem = col & 1023;
                    int h = rem >> 6, d = rem & 63;
                    int b = m >> 11, t = m & 2047;
                    if (which == 0) {
                        // fold softmax scale AND log2(e): 0.125 * 1.4426950408889634
                        q[((size_t)((b * HH + h) * TT + t)) * DHH + d] = f2b(val * 0.18033688011112042f);
                    } else if (which == 1) {
                        k[((size_t)((b * HH + h) * TT + t)) * DHH + d] = f2b(val);
                    } else {
                        vt[((size_t)((b * HH + h) * DHH + d)) * TT + t] = f2b(val);
                    }
                } else {
                    outf[(size_t)m * N + col] = val;
                }
            }
        }
    }
}

// ---------------- flash attention, swapped-operand 32x32 structure ----------------
// grid 512 blocks (XCD-swizzled), 4 waves/block, each wave owns 32 q-rows.
// S^T = K*Q^T (lane owns one q-row = lane&31), softmax per-lane scalar state,
// P -> B-frag via cvt_pk_bf16 + permlane32_swap (no LDS round trip),
// O^T = V^T * P^T (vt pre-transposed), rescale is per-lane scalar.
__global__ __launch_bounds__(256) void attn(
    const unsigned short* __restrict__ qb,
    const unsigned short* __restrict__ kb,
    const unsigned short* __restrict__ vtb,
    unsigned short* __restrict__ ob)
{
    __shared__ unsigned short Ks[64 * 64];
    __shared__ unsigned short Vs[64 * 64];

    int tid = threadIdx.x;
    int l = tid & 63, w = tid >> 6;
    int hi = l >> 5, c = l & 31;

    // XCD swizzle: same-XCD hw blocks get consecutive work -> 4 heads' K/V per XCD L2
    int lin = blockIdx.y * gridDim.x + blockIdx.x;       // 0..511
    int swz = (lin & 7) * 64 + (lin >> 3);
    int bh = swz >> 4;
    int qrow = (swz & 15) * 128 + w * 32 + c;

    // Q as B-fragments: col = qrow (lane&31), k = d = kd*16 + hi*8 + j
    bf16x8 qf[4];
    const unsigned short* qg = qb + ((size_t)bh * TT + qrow) * DHH;
#pragma unroll
    for (int kd = 0; kd < 4; ++kd)
        qf[kd] = *(const bf16x8*)(qg + kd * 16 + hi * 8);

    f32x16 oa0 = {}, oa1 = {};
    float m = -1e30f, lsum = 0.f;

    const char* kgl = (const char*)(kb + (size_t)bh * TT * DHH);
    const char* vgl = (const char*)(vtb + (size_t)bh * DHH * TT);

    for (int kt0 = 0; kt0 < TT; kt0 += 64) {
        // stage K [64 key][64 d] and Vt [64 d][64 key]; rows = 128B, XOR-swizzled
        // via pre-swizzled global source (gl_lds dest must stay linear)
#pragma unroll
        for (int r = 0; r < 2; ++r) {
            int p = r * 4096 + tid * 16;
            int rw = p >> 7, qq = p & 127;
            int sw = qq ^ ((rw & 7) << 4);
            gl_lds16(kgl + (size_t)(kt0 + rw) * 128 + sw, (char*)Ks + p);
            gl_lds16(vgl + (size_t)rw * (TT * 2) + kt0 * 2 + sw, (char*)Vs + p);
        }
        __syncthreads();

        // S^T = K * Q^T : D rows = key (crow), cols = q-row (lane&31)
        f32x16 s0 = {}, s1 = {};
#pragma unroll
        for (int kd = 0; kd < 4; ++kd) {
            int cb = (kd * 16 + hi * 8) * 2;
            bf16x8 kf0 = *(const bf16x8*)((const char*)Ks + c * 128 + (cb ^ ((c & 7) << 4)));
            bf16x8 kf1 = *(const bf16x8*)((const char*)Ks + (32 + c) * 128 + (cb ^ ((c & 7) << 4)));
            s0 = mfma32(kf0, qf[kd], s0);
            s1 = mfma32(kf1, qf[kd], s1);
        }

        // online softmax (log2 domain; scale*log2e folded into q)
        float tm = s0[0];
#pragma unroll
        for (int r = 1; r < 16; ++r) tm = fmaxf(tm, s0[r]);
#pragma unroll
        for (int r = 0; r < 16; ++r) tm = fmaxf(tm, s1[r]);
        tm = fmaxf(tm, __shfl_xor(tm, 32, 64));

        float nm = fmaxf(m, tm);
        if (!__all(nm - m <= 8.f)) {            // T13: defer rescale unless max grew >8
            float corr = fexp2(m - nm);
            lsum *= corr;
#pragma unroll
            for (int r = 0; r < 16; ++r) { oa0[r] *= corr; oa1[r] *= corr; }
            m = nm;
        }

        float psum = 0.f;
#pragma unroll
        for (int r = 0; r < 16; ++r) { s0[r] = fexp2(s0[r] - m); psum += s0[r]; }
#pragma unroll
        for (int r = 0; r < 16; ++r) { s1[r] = fexp2(s1[r] - m); psum += s1[r]; }
        psum += __shfl_xor(psum, 32);
        lsum += psum;

        // P^T -> B-fragments (4 u32 each, 16 keys per frag): cvt_pk + permlane32_swap
        u32x4 pf0, pf1, pf2, pf3;
#define MKFRAG(sv, base, dst) { \
        unsigned int c0 = pkbf(sv[base+0], sv[base+1]); \
        unsigned int c1 = pkbf(sv[base+2], sv[base+3]); \
        unsigned int c2 = pkbf(sv[base+4], sv[base+5]); \
        unsigned int c3 = pkbf(sv[base+6], sv[base+7]); \
        pl32swap(c0, c2); pl32swap(c1, c3); \
        dst[0] = c0; dst[1] = c1; dst[2] = c2; dst[3] = c3; }
        MKFRAG(s0, 0, pf0)
        MKFRAG(s0, 8, pf1)
        MKFRAG(s1, 0, pf2)
        MKFRAG(s1, 8, pf3)
#undef MKFRAG

        // O^T += V^T * P^T : A = Vt (row = d), B = P (col = q-row)
#define PVSTEP(kc, pf) { \
        int cb = (kc * 16 + hi * 8) * 2; \
        bf16x8 vf0 = *(const bf16x8*)((const char*)Vs + c * 128 + (cb ^ ((c & 7) << 4))); \
        bf16x8 vf1 = *(const bf16x8*)((const char*)Vs + (32 + c) * 128 + (cb ^ ((c & 7) << 4))); \
        bf16x8 ph = u2h(pf); \
        oa0 = mfma32(vf0, ph, oa0); \
        oa1 = mfma32(vf1, ph, oa1); }
        PVSTEP(0, pf0)
        PVSTEP(1, pf1)
        PVSTEP(2, pf2)
        PVSTEP(3, pf3)
#undef PVSTEP

        __syncthreads();
    }

    // normalize, write O^T back as O[b, t, h*64 + d]
    float rn = 1.0f / lsum;
    int b = bh >> 4, h = bh & 15;
    unsigned short* obase = ob + ((size_t)(b * TT + qrow)) * DD + h * 64;
#pragma unroll
    for (int g = 0; g < 4; ++g) {
        u16x4 o0, o1;
#pragma unroll
        for (int e = 0; e < 4; ++e) {
            o0[e] = f2b(oa0[g * 4 + e] * rn);
            o1[e] = f2b(oa1[g * 4 + e] * rn);
        }
        *(u16x4*)(obase + 8 * g + 4 * hi)      = o0;   // d = e + 8g + 4hi (db=0)
        *(u16x4*)(obase + 32 + 8 * g + 4 * hi) = o1;   // db=1
    }
}

// ---------------- launcher ----------------
extern "C" void kernel_launch(void* const* d_in, const int* in_sizes, int n_in,
                              void* d_out, int out_size, void* d_ws, size_t ws_size,
                              hipStream_t stream) {
    const float* x    = (const float*)d_in[0];
    const float* Wqkv = (const float*)d_in[1];
    const float* bqkv = (const float*)d_in[2];
    const float* Wo   = (const float*)d_in[3];
    const float* bo   = (const float*)d_in[4];
    float* out = (float*)d_out;

    unsigned short* xb  = (unsigned short*)d_ws;        // [4096,1024]
    unsigned short* wqb = xb  + 4096 * 1024;            // [3072,1024]
    unsigned short* wob = wqb + 3072 * 1024;            // [1024,1024]
    unsigned short* q   = wob + 1024 * 1024;            // [B,H,T,DH]
    unsigned short* k   = q   + 2 * 16 * 2048 * 64;     // [B,H,T,DH]
    unsigned short* vt  = k   + 2 * 16 * 2048 * 64;     // [B,H,DH,T]
    unsigned short* ob  = vt  + 2 * 16 * 2048 * 64;     // [4096,1024]

    f2b_kernel<<<dim3(1024), dim3(256), 0, stream>>>(x,    xb,  4096 * 1024 / 4);
    f2b_kernel<<<dim3(768),  dim3(256), 0, stream>>>(Wqkv, wqb, 3072 * 1024 / 4);
    f2b_kernel<<<dim3(256),  dim3(256), 0, stream>>>(Wo,   wob, 1024 * 1024 / 4);

    // QKV projection: M=4096, N=3072, K=1024
    gemm_bt<<<dim3(24, 32), dim3(256), 0, stream>>>(xb, wqb, bqkv, 3072, 1024, 0,
                                                    q, k, vt, nullptr);
    // attention: 512 blocks, 4 waves each
    attn<<<dim3(16, 32), dim3(256), 0, stream>>>(q, k, vt, ob);

    // output projection: M=4096, N=1024, K=1024
    gemm_bt<<<dim3(8, 32), dim3(256), 0, stream>>>(ob, wob, bo, 1024, 1024, 1,
                                                   nullptr, nullptr, nullptr, out);
}

// Round 3
// 128.987 us; speedup vs baseline: 1.5955x; 1.0885x over previous
//
#include <hip/hip_runtime.h>

// Problem constants: B=2, T=2048, D=1024, H=16, DH=64
#define TT 2048
#define DD 1024
#define HH 16
#define DHH 64

typedef __attribute__((ext_vector_type(4)))  float  f32x4;
typedef __attribute__((ext_vector_type(16))) float  f32x16;
typedef __attribute__((ext_vector_type(8)))  short  bf16x8;   // 8 bf16 in 4 VGPRs
typedef __attribute__((ext_vector_type(4)))  float  f4;
typedef __attribute__((ext_vector_type(4)))  unsigned short u16x4;
typedef __attribute__((ext_vector_type(4)))  unsigned int   u32x4;

// fp32 -> bf16 round-to-nearest-even
__device__ __forceinline__ unsigned short f2b(float f) {
    union { float f; unsigned int u; } v; v.f = f;
    unsigned int r = v.u + 0x7fffu + ((v.u >> 16) & 1u);
    return (unsigned short)(r >> 16);
}

// async global->LDS, 16B per lane; LDS dest must be wave-uniform base + lane*16
__device__ __forceinline__ void gl_lds16(const void* g, void* l) {
    __builtin_amdgcn_global_load_lds(
        (const __attribute__((address_space(1))) unsigned int*)g,
        (__attribute__((address_space(3))) unsigned int*)l, 16, 0, 0);
}

__device__ __forceinline__ f32x16 mfma32(bf16x8 a, bf16x8 b, f32x16 c) {
    return __builtin_amdgcn_mfma_f32_32x32x16_bf16(a, b, c, 0, 0, 0);
}

// 2^x via v_exp_f32
__device__ __forceinline__ float fexp2(float x) {
    float r; asm("v_exp_f32 %0, %1" : "=v"(r) : "v"(x)); return r;
}

// pack two f32 -> u32 of 2 bf16 (lo = a, hi = b)
__device__ __forceinline__ unsigned int pkbf(float a, float b) {
    unsigned int r;
    asm("v_cvt_pk_bf16_f32 %0, %1, %2" : "=v"(r) : "v"(a), "v"(b));
    return r;
}

// v_permlane32_swap_b32: a'[32+i]=b[i]; b'[i]=a[32+i]
__device__ __forceinline__ void pl32swap(unsigned int& a, unsigned int& b) {
    asm("v_permlane32_swap_b32 %0, %1" : "+v"(a), "+v"(b));
}

__device__ __forceinline__ bf16x8 u2h(u32x4 u) {
    union { u32x4 u; bf16x8 h; } x; x.u = u; return x.h;
}

// ---------------- fp32 -> bf16 conversion (vectorized) ----------------
__global__ void f2b_kernel(const float* __restrict__ s, unsigned short* __restrict__ d, int n4) {
    int i = blockIdx.x * blockDim.x + threadIdx.x;
    int stride = gridDim.x * blockDim.x;
    for (; i < n4; i += stride) {
        f4 v = ((const f4*)s)[i];
        u16x4 o;
        o[0] = f2b(v[0]); o[1] = f2b(v[1]); o[2] = f2b(v[2]); o[3] = f2b(v[3]);
        ((u16x4*)d)[i] = o;
    }
}

// ---------------- GEMM: C[M,N] = A[M,K] * Bm[N,K]^T + bias ----------------
// 128 x BN tile, 4 waves (2x2), 2-phase double-buffered LDS staging.
// MODE 0 (BN=128): QKV epilogue -> q scaled by 0.125*log2e, k [B,H,T,DH], vt [B,H,DH,T]
// MODE 1 (BN=64):  fp32 out + bias (final projection; BN=64 -> 512 blocks)
template<int BN, int MODE>
__global__ __launch_bounds__(256) void gemm_bt(
    const unsigned short* __restrict__ A, const unsigned short* __restrict__ Bm,
    const float* __restrict__ bias, int N, int K,
    unsigned short* __restrict__ q, unsigned short* __restrict__ k,
    unsigned short* __restrict__ vt, float* __restrict__ outf)
{
    constexpr int NB  = BN / 32;        // B-frags per wave
    constexpr int ASZ = 128 * 32;       // shorts per A tile
    constexpr int BSZ = BN * 32;        // shorts per B tile
    __shared__ unsigned short lds[2 * (ASZ + BSZ)];

    int tid = threadIdx.x;
    int l = tid & 63, w = tid >> 6;
    int wr = w >> 1, wc = w & 1;
    int lr = l & 15, lk = (l >> 4) * 8;
    int bm = blockIdx.y, bn = blockIdx.x;

    f32x4 acc[4][NB] = {};

    const unsigned short* Ag = A + (size_t)(bm * 128) * K;
    const unsigned short* Bg = Bm + (size_t)(bn * BN) * K;

    auto stage = [&](int buf, int k0) {
        unsigned short* As = lds + buf * (ASZ + BSZ);
        unsigned short* Bs = As + ASZ;
#pragma unroll
        for (int r = 0; r < 2; ++r) {
            int e = r * 256 + tid;
            int row = e >> 2, kc = (e & 3) * 8;
            gl_lds16(Ag + (size_t)row * K + k0 + kc, &As[e * 8]);
        }
#pragma unroll
        for (int r = 0; r < BN / 64; ++r) {
            int e = r * 256 + tid;
            int row = e >> 2, kc = (e & 3) * 8;
            gl_lds16(Bg + (size_t)row * K + k0 + kc, &Bs[e * 8]);
        }
    };

    stage(0, 0);
    __syncthreads();                     // barrier drain waits vmcnt(0) too
    int cur = 0;
    for (int k0 = 0; k0 < K; k0 += 32) {
        if (k0 + 32 < K) stage(cur ^ 1, k0 + 32);   // prefetch next tile
        const unsigned short* As = lds + cur * (ASZ + BSZ);
        const unsigned short* Bs = As + ASZ;
        bf16x8 a[4], b[NB];
#pragma unroll
        for (int i = 0; i < 4; ++i)
            a[i] = *(const bf16x8*)&As[(wr * 64 + i * 16 + lr) * 32 + lk];
#pragma unroll
        for (int j = 0; j < NB; ++j)
            b[j] = *(const bf16x8*)&Bs[(wc * (BN / 2) + j * 16 + lr) * 32 + lk];
#pragma unroll
        for (int i = 0; i < 4; ++i)
#pragma unroll
            for (int j = 0; j < NB; ++j)
                acc[i][j] = __builtin_amdgcn_mfma_f32_16x16x32_bf16(a[i], b[j], acc[i][j], 0, 0, 0);
        __syncthreads();                 // waits prefetch done + all reads done
        cur ^= 1;
    }

#pragma unroll
    for (int i = 0; i < 4; ++i) {
#pragma unroll
        for (int j = 0; j < NB; ++j) {
            int row0 = bm * 128 + wr * 64 + i * 16 + (l >> 4) * 4;
            int col  = bn * BN + wc * (BN / 2) + j * 16 + (l & 15);
            float bv = bias[col];
#pragma unroll
            for (int r = 0; r < 4; ++r) {
                float val = acc[i][j][r] + bv;
                int m = row0 + r;
                if (MODE == 0) {
                    int which = col >> 10, rem = col & 1023;
                    int h = rem >> 6, d = rem & 63;
                    int b = m >> 11, t = m & 2047;
                    if (which == 0) {
                        // fold softmax scale AND log2(e): 0.125 * 1.4426950408889634
                        q[((size_t)((b * HH + h) * TT + t)) * DHH + d] = f2b(val * 0.18033688011112042f);
                    } else if (which == 1) {
                        k[((size_t)((b * HH + h) * TT + t)) * DHH + d] = f2b(val);
                    } else {
                        vt[((size_t)((b * HH + h) * DHH + d)) * TT + t] = f2b(val);
                    }
                } else {
                    outf[(size_t)m * N + col] = val;
                }
            }
        }
    }
}

// ---------------- flash attention, swapped-operand 32x32, 2-phase dbuf ----------------
// grid 512 blocks (XCD-swizzled), 4 waves/block, each wave owns 32 q-rows.
// S^T = K*Q^T (lane owns one q-row = lane&31), softmax per-lane scalar state,
// P -> B-frag via cvt_pk_bf16 + permlane32_swap (no LDS round trip),
// O^T = V^T * P^T (vt pre-transposed), rescale per-lane scalar.
// K/V tiles double-buffered: prefetch t+1 issued before compute of t.
__global__ __launch_bounds__(256) void attn(
    const unsigned short* __restrict__ qb,
    const unsigned short* __restrict__ kb,
    const unsigned short* __restrict__ vtb,
    unsigned short* __restrict__ ob)
{
    __shared__ char lds[32768];          // [buf][Ks 8KB | Vs 8KB] x2

    int tid = threadIdx.x;
    int l = tid & 63, w = tid >> 6;
    int hi = l >> 5, c = l & 31;

    // XCD swizzle: 4 heads' K/V per XCD L2
    int lin = blockIdx.y * gridDim.x + blockIdx.x;       // 0..511
    int swz = (lin & 7) * 64 + (lin >> 3);
    int bh = swz >> 4;
    int qrow = (swz & 15) * 128 + w * 32 + c;

    // Q as B-fragments: col = qrow (lane&31), k = d = kd*16 + hi*8 + j
    bf16x8 qf[4];
    const unsigned short* qg = qb + ((size_t)bh * TT + qrow) * DHH;
#pragma unroll
    for (int kd = 0; kd < 4; ++kd)
        qf[kd] = *(const bf16x8*)(qg + kd * 16 + hi * 8);

    f32x16 oa0 = {}, oa1 = {};
    float m = -1e30f, lsum = 0.f;

    const char* kgl = (const char*)(kb + (size_t)bh * TT * DHH);
    const char* vgl = (const char*)(vtb + (size_t)bh * DHH * TT);

    // stage K [64 key][64 d] and Vt [64 d][64 key]; rows 128B, XOR-swizzled
    // via pre-swizzled global source (gl_lds dest must stay linear)
    auto stage = [&](int buf, int kt0) {
#pragma unroll
        for (int r = 0; r < 2; ++r) {
            int p = r * 4096 + tid * 16;
            int rw = p >> 7, qq = p & 127;
            int sw = qq ^ ((rw & 7) << 4);
            gl_lds16(kgl + (size_t)(kt0 + rw) * 128 + sw, lds + buf * 16384 + p);
            gl_lds16(vgl + (size_t)rw * (TT * 2) + kt0 * 2 + sw, lds + buf * 16384 + 8192 + p);
        }
    };

    stage(0, 0);
    __syncthreads();
    int cur = 0;

    for (int kt0 = 0; kt0 < TT; kt0 += 64) {
        if (kt0 + 64 < TT) stage(cur ^ 1, kt0 + 64);   // prefetch next K/V tile
        const char* Ksb = lds + cur * 16384;
        const char* Vsb = Ksb + 8192;

        // S^T = K * Q^T : D rows = key (crow), cols = q-row (lane&31)
        f32x16 s0 = {}, s1 = {};
#pragma unroll
        for (int kd = 0; kd < 4; ++kd) {
            int cb = (kd * 16 + hi * 8) * 2;
            bf16x8 kf0 = *(const bf16x8*)(Ksb + c * 128 + (cb ^ ((c & 7) << 4)));
            bf16x8 kf1 = *(const bf16x8*)(Ksb + (32 + c) * 128 + (cb ^ ((c & 7) << 4)));
            s0 = mfma32(kf0, qf[kd], s0);
            s1 = mfma32(kf1, qf[kd], s1);
        }

        // online softmax (log2 domain); tree max
        float mx[16];
#pragma unroll
        for (int r = 0; r < 16; ++r) mx[r] = fmaxf(s0[r], s1[r]);
#pragma unroll
        for (int d = 8; d >= 1; d >>= 1)
#pragma unroll
            for (int r = 0; r < d; ++r) mx[r] = fmaxf(mx[r], mx[r + d]);
        float tm = fmaxf(mx[0], __shfl_xor(mx[0], 32, 64));

        float nm = fmaxf(m, tm);
        if (!__all(nm - m <= 8.f)) {            // T13: defer rescale unless max grew >8
            float corr = fexp2(m - nm);
            lsum *= corr;
#pragma unroll
            for (int r = 0; r < 16; ++r) { oa0[r] *= corr; oa1[r] *= corr; }
            m = nm;
        }

        float p4[4] = {0.f, 0.f, 0.f, 0.f};
#pragma unroll
        for (int r = 0; r < 16; ++r) { s0[r] = fexp2(s0[r] - m); p4[r & 3] += s0[r]; }
#pragma unroll
        for (int r = 0; r < 16; ++r) { s1[r] = fexp2(s1[r] - m); p4[r & 3] += s1[r]; }
        float psum = (p4[0] + p4[1]) + (p4[2] + p4[3]);
        psum += __shfl_xor(psum, 32);
        lsum += psum;

        // P^T -> B-fragments (4 u32 each, 16 keys per frag): cvt_pk + permlane32_swap
        u32x4 pf0, pf1, pf2, pf3;
#define MKFRAG(sv, base, dst) { \
        unsigned int c0 = pkbf(sv[base+0], sv[base+1]); \
        unsigned int c1 = pkbf(sv[base+2], sv[base+3]); \
        unsigned int c2 = pkbf(sv[base+4], sv[base+5]); \
        unsigned int c3 = pkbf(sv[base+6], sv[base+7]); \
        pl32swap(c0, c2); pl32swap(c1, c3); \
        dst[0] = c0; dst[1] = c1; dst[2] = c2; dst[3] = c3; }
        MKFRAG(s0, 0, pf0)
        MKFRAG(s0, 8, pf1)
        MKFRAG(s1, 0, pf2)
        MKFRAG(s1, 8, pf3)
#undef MKFRAG

        // O^T += V^T * P^T : A = Vt (row = d), B = P (col = q-row)
#define PVSTEP(kc, pf) { \
        int cb = (kc * 16 + hi * 8) * 2; \
        bf16x8 vf0 = *(const bf16x8*)(Vsb + c * 128 + (cb ^ ((c & 7) << 4))); \
        bf16x8 vf1 = *(const bf16x8*)(Vsb + (32 + c) * 128 + (cb ^ ((c & 7) << 4))); \
        bf16x8 ph = u2h(pf); \
        oa0 = mfma32(vf0, ph, oa0); \
        oa1 = mfma32(vf1, ph, oa1); }
        PVSTEP(0, pf0)
        PVSTEP(1, pf1)
        PVSTEP(2, pf2)
        PVSTEP(3, pf3)
#undef PVSTEP

        __syncthreads();                 // prefetch landed + all reads done
        cur ^= 1;
    }

    // normalize, write O^T back as O[b, t, h*64 + d]
    float rn = 1.0f / lsum;
    int b = bh >> 4, h = bh & 15;
    unsigned short* obase = ob + ((size_t)(b * TT + qrow)) * DD + h * 64;
#pragma unroll
    for (int g = 0; g < 4; ++g) {
        u16x4 o0, o1;
#pragma unroll
        for (int e = 0; e < 4; ++e) {
            o0[e] = f2b(oa0[g * 4 + e] * rn);
            o1[e] = f2b(oa1[g * 4 + e] * rn);
        }
        *(u16x4*)(obase + 8 * g + 4 * hi)      = o0;   // d = e + 8g + 4hi (db=0)
        *(u16x4*)(obase + 32 + 8 * g + 4 * hi) = o1;   // db=1
    }
}

// ---------------- launcher ----------------
extern "C" void kernel_launch(void* const* d_in, const int* in_sizes, int n_in,
                              void* d_out, int out_size, void* d_ws, size_t ws_size,
                              hipStream_t stream) {
    const float* x    = (const float*)d_in[0];
    const float* Wqkv = (const float*)d_in[1];
    const float* bqkv = (const float*)d_in[2];
    const float* Wo   = (const float*)d_in[3];
    const float* bo   = (const float*)d_in[4];
    float* out = (float*)d_out;

    unsigned short* xb  = (unsigned short*)d_ws;        // [4096,1024]
    unsigned short* wqb = xb  + 4096 * 1024;            // [3072,1024]
    unsigned short* wob = wqb + 3072 * 1024;            // [1024,1024]
    unsigned short* q   = wob + 1024 * 1024;            // [B,H,T,DH]
    unsigned short* k   = q   + 2 * 16 * 2048 * 64;     // [B,H,T,DH]
    unsigned short* vt  = k   + 2 * 16 * 2048 * 64;     // [B,H,DH,T]
    unsigned short* ob  = vt  + 2 * 16 * 2048 * 64;     // [4096,1024]

    f2b_kernel<<<dim3(1024), dim3(256), 0, stream>>>(x,    xb,  4096 * 1024 / 4);
    f2b_kernel<<<dim3(768),  dim3(256), 0, stream>>>(Wqkv, wqb, 3072 * 1024 / 4);
    f2b_kernel<<<dim3(256),  dim3(256), 0, stream>>>(Wo,   wob, 1024 * 1024 / 4);

    // QKV projection: M=4096, N=3072, K=1024
    gemm_bt<128, 0><<<dim3(24, 32), dim3(256), 0, stream>>>(xb, wqb, bqkv, 3072, 1024,
                                                            q, k, vt, nullptr);
    // attention: 512 blocks, 4 waves each
    attn<<<dim3(16, 32), dim3(256), 0, stream>>>(q, k, vt, ob);

    // output projection: M=4096, N=1024, K=1024 (BN=64 -> 512 blocks)
    gemm_bt<64, 1><<<dim3(16, 32), dim3(256), 0, stream>>>(ob, wob, bo, 1024, 1024,
                                                           nullptr, nullptr, nullptr, out);
}